// Round 11
// baseline (91.757 us; speedup 1.0000x reference)
//
#include <hip/hip_runtime.h>

#define NTOT 1536
#define DD 2048
#define BB 4
#define SS 4096
#define NBB 42          // partial blocks per (group,b)
#define TPB 98          // ceil(4096/42)
#define NTILE 7         // 7*16 = 112 >= 98 token slots per block

typedef __attribute__((ext_vector_type(8))) short bf16x8;
typedef __attribute__((ext_vector_type(4))) float f32x4;

__device__ __forceinline__ void split1(float v, unsigned short& hi, unsigned short& lo) {
  unsigned u = __float_as_uint(v);
  hi = (unsigned short)(u >> 16);
  float hf = __uint_as_float(u & 0xffff0000u);
  float r = v - hf;
  lo = (unsigned short)(__float_as_uint(r) >> 16);
}

// async 16B global->LDS (no VGPR round-trip); LDS dest = wave base + lane*16,
// global src is per-lane (pre-swizzled where needed, m173 pattern)
__device__ __forceinline__ void gload16(const void* g, void* lds) {
  __builtin_amdgcn_global_load_lds(
      (const __attribute__((address_space(1))) unsigned int*)g,
      (__attribute__((address_space(3))) unsigned int*)lds, 16, 0, 0);
}

// ---------------- kernel 0: merged prep (emb normalize + W images) -------------
__global__ __launch_bounds__(256) void k_prep(const float* __restrict__ emb,
                                              const float* __restrict__ W,
                                              short* __restrict__ eH,
                                              short* __restrict__ eL,
                                              short* __restrict__ imgH,
                                              short* __restrict__ imgL) {
  int bid = blockIdx.x;
  if (bid < 384) {
    int wave = threadIdx.x >> 6;
    int lane = threadIdx.x & 63;
    int n = bid * 4 + wave;               // 384*4 = 1536 exactly
    float v = emb[n * 64 + lane];
    float ss = v * v;
#pragma unroll
    for (int off = 32; off; off >>= 1) ss += __shfl_xor(ss, off, 64);
    float nrm = fmaxf(sqrtf(ss), 1e-12f);
    float nv = v / nrm;
    unsigned short hi, lo;
    split1(nv, hi, lo);
    eH[n * 64 + lane] = (short)hi;
    eL[n * 64 + lane] = (short)lo;
  } else {
    int kt = bid - 384;                   // 0..31
    for (int idx = threadIdx.x; idx < 4096; idx += 256) {
      int n = idx & 63;
      int q = idx >> 6;          // 0..63
      int p = q >> 3;            // phys slot
      int e = q & 7;
      int s = p ^ (n & 7);       // logical slot
      int k = kt * 64 + s * 8 + e;
      float v = W[k * 64 + n];
      unsigned short hi, lo;
      split1(v, hi, lo);
      int flat = kt * 4096 + n * 64 + p * 8 + e;
      imgH[flat] = (short)hi;
      imgL[flat] = (short)lo;
    }
  }
}

// ---------------- kernel 1: h = x @ W + b via hi/lo bf16 MFMA -> hi/lo h ----------
// 256 thr (4 waves), tile 32 tok x 64 n, K-tile 64. Staging via global_load_lds
// width=16 (zero reg staging). COUNTED vmcnt pipeline (T3+T4): depth-2, loads
// for tiles kt+1/kt+2 stay in flight across raw s_barriers; vmcnt(6) (one
// tile = 6 loads/wave) instead of the compiler's vmcnt(0) drain at
// __syncthreads — that drain was the ~30%-over-floor stall (m97 ceiling).
__global__ __launch_bounds__(256, 2) void k_proj(const float* __restrict__ x,
                                                 const float* __restrict__ imgHf,
                                                 const float* __restrict__ imgLf,
                                                 const float* __restrict__ bias,
                                                 short* __restrict__ hH,
                                                 short* __restrict__ hL) {
  __shared__ float XAs[2][2048];   // [tok 0..31][64 k]; phys slot p holds logical p^(tok&7)
  __shared__ short BHs[2][4096];   // bf16 hi image tile (pre-swizzled in ws)
  __shared__ short BLs[2][4096];

  int tid = threadIdx.x;           // 0..255
  int w = tid >> 6;                // 0..3
  int l = tid & 63;
  size_t t0 = (size_t)blockIdx.x * 32;

  int th = (w & 1) * 16;           // token half
  int nh = (w >> 1) * 32;          // n half

  f32x4 acc[2];
#pragma unroll
  for (int i = 0; i < 2; ++i) acc[i] = (f32x4){0.f, 0.f, 0.f, 0.f};

  const float4* imgH4 = (const float4*)imgHf;
  const float4* imgL4 = (const float4*)imgLf;

  // per-lane staging geometry, constant across kt
  size_t xoff[2];     // float index into x for KT=0 (+= KT*64 per tile)
  int xdst[2];        // float index into XAs[DB]
  int ioff[2];        // float4 index into img (+= KT*512 per tile)
  int bdst[2];        // short index into BHs/BLs[DB]
#pragma unroll
  for (int c = 0; c < 2; ++c) {
    int tok = c * 16 + w * 4 + (l >> 4);
    int s = (l & 15) ^ (tok & 7);                 // logical slot for this phys slot
    xoff[c] = (t0 + tok) * DD + s * 4;
    xdst[c] = tok * 64 + (l & 15) * 4;            // == wave base + l*16B (linear)
    ioff[c] = c * 256 + tid;
    bdst[c] = (c * 256 + tid) * 8;                // == wave base + l*16B (linear)
  }

#define STAGE(DB, KT)                                                        \
  {                                                                          \
    _Pragma("unroll") for (int c = 0; c < 2; ++c) {                          \
      gload16(x + xoff[c] + (KT) * 64, &XAs[DB][xdst[c]]);                   \
      gload16(imgH4 + (KT) * 512 + ioff[c], &BHs[DB][bdst[c]]);              \
      gload16(imgL4 + (KT) * 512 + ioff[c], &BLs[DB][bdst[c]]);              \
    }                                                                        \
  }

#define COMPUTE(DB)                                                                \
  {                                                                                \
    int row = th + (l & 15);                                                       \
    _Pragma("unroll") for (int ks = 0; ks < 2; ++ks) {                             \
      int s0 = ks * 8 + (l >> 4) * 2;                                              \
      float4 xa = *(const float4*)(&XAs[DB][row * 64 + ((s0 ^ (row & 7)) << 2)]);  \
      float4 xb = *(const float4*)(&XAs[DB][row * 64 + (((s0 + 1) ^ (row & 7)) << 2)]); \
      bf16x8 ahi, alo;                                                             \
      {                                                                            \
        float v[8] = {xa.x, xa.y, xa.z, xa.w, xb.x, xb.y, xb.z, xb.w};             \
        _Pragma("unroll") for (int i = 0; i < 8; ++i) {                            \
          unsigned u = __float_as_uint(v[i]);                                      \
          ahi[i] = (short)(u >> 16);                                               \
          float hf = __uint_as_float(u & 0xffff0000u);                             \
          float r = v[i] - hf;                                                     \
          alo[i] = (short)(__float_as_uint(r) >> 16);                              \
        }                                                                          \
      }                                                                            \
      _Pragma("unroll") for (int nf = 0; nf < 2; ++nf) {                           \
        int n = nh + nf * 16 + (l & 15);                                           \
        int p = (ks * 4 + (l >> 4)) ^ (n & 7);                                     \
        bf16x8 bh = *(const bf16x8*)(&BHs[DB][n * 64 + p * 8]);                    \
        bf16x8 bl = *(const bf16x8*)(&BLs[DB][n * 64 + p * 8]);                    \
        acc[nf] = __builtin_amdgcn_mfma_f32_16x16x32_bf16(ahi, bh, acc[nf], 0, 0, 0); \
        acc[nf] = __builtin_amdgcn_mfma_f32_16x16x32_bf16(alo, bh, acc[nf], 0, 0, 0); \
        acc[nf] = __builtin_amdgcn_mfma_f32_16x16x32_bf16(ahi, bl, acc[nf], 0, 0, 0); \
      }                                                                            \
    }                                                                              \
  }

  // depth-2 prologue: tiles 0 and 1 in flight (12 outstanding vmem/wave)
  STAGE(0, 0);
  STAGE(1, 1);

  int db = 0;
#pragma unroll 1
  for (int kt = 0; kt < 32; ++kt) {
    // wait for tile kt's 6 loads; tile kt+1's 6 stay in flight (last iter: 0)
    if (kt < 31) {
      asm volatile("s_waitcnt vmcnt(6)" ::: "memory");
    } else {
      asm volatile("s_waitcnt vmcnt(0)" ::: "memory");
    }
    __builtin_amdgcn_sched_barrier(0);
    __builtin_amdgcn_s_barrier();        // buf[db] ready for all waves
    __builtin_amdgcn_sched_barrier(0);
    COMPUTE(db);
    __builtin_amdgcn_sched_barrier(0);
    __builtin_amdgcn_s_barrier();        // all waves done reading buf[db]
    __builtin_amdgcn_sched_barrier(0);
    if (kt < 30) STAGE(db, kt + 2);      // safe to overwrite now
    db ^= 1;
  }

  // epilogue: token = t0 + th + (l>>4)*4+j, n = nh + nf*16 + (l&15)
#pragma unroll
  for (int nf = 0; nf < 2; ++nf) {
    int n = nh + nf * 16 + (l & 15);
    float bv = bias[n];
#pragma unroll
    for (int j = 0; j < 4; ++j) {
      size_t tok = t0 + th + (l >> 4) * 4 + j;
      float v = acc[nf][j] + bv;
      unsigned short hi, lo;
      split1(v, hi, lo);
      hH[tok * 64 + n] = (short)hi;
      hL[tok * 64 + n] = (short)lo;
    }
  }
#undef STAGE
#undef COMPUTE
}

// ---------------- kernel 2: MFMA logits -> softmax -> importance pooling ----------
__global__ __launch_bounds__(512, 2) void k_pref(const short* __restrict__ hH,
                                                 const short* __restrict__ hL,
                                                 const short* __restrict__ eH,
                                                 const short* __restrict__ eL,
                                                 const float* __restrict__ imp,
                                                 float* __restrict__ partials) {
  int bid = blockIdx.x;
  int g = bid / (BB * NBB);
  int rem = bid % (BB * NBB);
  int b = rem / NBB;
  int nb = rem % NBB;
  int tid = threadIdx.x;
  int w = tid >> 6;
  int l = tid & 63;
  int col = l & 15;
  int q = l >> 4;

  __shared__ short BLs[4 * 2 * 512 * 8];   // 65536 B: [nf][ks][tid] 16B slots
  __shared__ float zred[2][8][16];

  bf16x8 BH[4][2];
  {
    const short* eHg = eH + ((size_t)(g * 512 + w * 64 + col)) * 64 + q * 8;
    const short* eLg = eL + ((size_t)(g * 512 + w * 64 + col)) * 64 + q * 8;
#pragma unroll
    for (int nf = 0; nf < 4; ++nf) {
#pragma unroll
      for (int ks = 0; ks < 2; ++ks) {
        BH[nf][ks] = *(const bf16x8*)(eHg + nf * 1024 + ks * 32);
        bf16x8 blv = *(const bf16x8*)(eLg + nf * 1024 + ks * 32);
        *(bf16x8*)(&BLs[((nf * 2 + ks) * 512 + tid) * 8]) = blv;
      }
    }
  }
  __syncthreads();

  int s0 = nb * TPB;
  int slim = s0 + TPB; if (slim > SS) slim = SS;
  float wsum[4] = {0.f, 0.f, 0.f, 0.f};
  int par = 0;

#define LOADA(TB, A0, A1, A2, A3)                                        \
  {                                                                      \
    int arow = (TB) + col; if (arow > SS - 1) arow = SS - 1;             \
    size_t hoff = ((size_t)b * SS + arow) * 64;                          \
    A0 = *(const bf16x8*)(hH + hoff + q * 8);                            \
    A1 = *(const bf16x8*)(hH + hoff + 32 + q * 8);                       \
    A2 = *(const bf16x8*)(hL + hoff + q * 8);                            \
    A3 = *(const bf16x8*)(hL + hoff + 32 + q * 8);                       \
  }

  bf16x8 AH0, AH1, AL0, AL1, nH0, nH1, nL0, nL1;
  LOADA(s0, AH0, AH1, AL0, AL1);

#pragma unroll 1
  for (int tile = 0; tile < NTILE; ++tile) {
    int tbase = s0 + tile * 16;
    if (tile < NTILE - 1) LOADA(tbase + 16, nH0, nH1, nL0, nL1);

    f32x4 acc[4];
#pragma unroll
    for (int nf = 0; nf < 4; ++nf) acc[nf] = (f32x4){0.f, 0.f, 0.f, 0.f};
#pragma unroll
    for (int nf = 0; nf < 4; ++nf) {
      bf16x8 bl0 = *(const bf16x8*)(&BLs[((nf * 2 + 0) * 512 + tid) * 8]);
      bf16x8 bl1 = *(const bf16x8*)(&BLs[((nf * 2 + 1) * 512 + tid) * 8]);
      acc[nf] = __builtin_amdgcn_mfma_f32_16x16x32_bf16(AH0, BH[nf][0], acc[nf], 0, 0, 0);
      acc[nf] = __builtin_amdgcn_mfma_f32_16x16x32_bf16(AL0, BH[nf][0], acc[nf], 0, 0, 0);
      acc[nf] = __builtin_amdgcn_mfma_f32_16x16x32_bf16(AH0, bl0, acc[nf], 0, 0, 0);
      acc[nf] = __builtin_amdgcn_mfma_f32_16x16x32_bf16(AH1, BH[nf][1], acc[nf], 0, 0, 0);
      acc[nf] = __builtin_amdgcn_mfma_f32_16x16x32_bf16(AL1, BH[nf][1], acc[nf], 0, 0, 0);
      acc[nf] = __builtin_amdgcn_mfma_f32_16x16x32_bf16(AH1, bl1, acc[nf], 0, 0, 0);
    }

    float zp[4];
#pragma unroll
    for (int j = 0; j < 4; ++j) {
      zp[j] = __expf(acc[0][j]) + __expf(acc[1][j]) +
              __expf(acc[2][j]) + __expf(acc[3][j]);
    }
#pragma unroll
    for (int off = 1; off <= 8; off <<= 1) {
#pragma unroll
      for (int j = 0; j < 4; ++j) zp[j] += __shfl_xor(zp[j], off, 64);
    }
    float zw = (col == 0) ? zp[0] : (col == 1) ? zp[1] : (col == 2) ? zp[2] : zp[3];
    if (col < 4) zred[par][w][q * 4 + col] = zw;
    __syncthreads();
    float r0, r1, r2, r3;
    {
#pragma unroll
      for (int j = 0; j < 4; ++j) {
        int t16 = q * 4 + j;
        float Z = 0.f;
#pragma unroll
        for (int ww = 0; ww < 8; ++ww) Z += zred[par][ww][t16];
        int s = tbase + t16;
        float iv = (s < slim) ? imp[(size_t)b * SS + s] : 0.f;
        float r = iv / Z;
        if (j == 0) r0 = r; else if (j == 1) r1 = r; else if (j == 2) r2 = r; else r3 = r;
      }
    }
#pragma unroll
    for (int nf = 0; nf < 4; ++nf) {
      wsum[nf] += __expf(acc[nf][0]) * r0 + __expf(acc[nf][1]) * r1 +
                  __expf(acc[nf][2]) * r2 + __expf(acc[nf][3]) * r3;
    }
    AH0 = nH0; AH1 = nH1; AL0 = nL0; AL1 = nL1;
    par ^= 1;
  }
#undef LOADA

#pragma unroll
  for (int nf = 0; nf < 4; ++nf) {
    wsum[nf] += __shfl_xor(wsum[nf], 16, 64);
    wsum[nf] += __shfl_xor(wsum[nf], 32, 64);
  }
  if (q == 0) {
    size_t base = ((size_t)(g * BB + b) * NBB + nb) * 512 + w * 64;
#pragma unroll
    for (int nf = 0; nf < 4; ++nf) partials[base + nf * 16 + col] = wsum[nf];
  }
}

// ---------------- kernel 3: reduce partials + top-k + renormalize ----------------
__global__ __launch_bounds__(512) void k_topk(const float* __restrict__ partials,
                                              float* __restrict__ out) {
  int g = blockIdx.x >> 2;   // 0..2
  int b = blockIdx.x & 3;
  int tid = threadIdx.x;     // neuron 0..511
  int wave = tid >> 6, lane = tid & 63;

  __shared__ float lv[8][8];
  __shared__ int li[8][8];

  // 4-way ILP partial sum
  float d0 = 0.f, d1 = 0.f, d2 = 0.f, d3 = 0.f;
  const float* p = partials + (size_t)(g * BB + b) * NBB * 512 + tid;
  int nb = 0;
  for (; nb + 4 <= NBB; nb += 4) {
    d0 += p[(nb + 0) * 512];
    d1 += p[(nb + 1) * 512];
    d2 += p[(nb + 2) * 512];
    d3 += p[(nb + 3) * 512];
  }
  for (; nb < NBB; ++nb) d0 += p[nb * 512];
  float dense = (d0 + d1) + (d2 + d3);

  int K = (g == 0) ? 8 : (g == 1) ? 4 : 6;
  float val = dense;
  float ssum = 0.f;
  int sel = 0;
  for (int it = 0; it < K; ++it) {
    float v = val;
    int idx = tid;
#pragma unroll
    for (int off = 32; off; off >>= 1) {
      float ov = __shfl_xor(v, off, 64);
      int oi = __shfl_xor(idx, off, 64);
      if (ov > v || (ov == v && oi < idx)) { v = ov; idx = oi; }
    }
    if (lane == 0) { lv[wave][0] = v; li[wave][0] = idx; }
    __syncthreads();
    float mv = lv[0][0];
    int mi = li[0][0];
#pragma unroll
    for (int ww = 1; ww < 8; ++ww) {
      float wv2 = lv[ww][0];
      int wi = li[ww][0];
      if (wv2 > mv || (wv2 == mv && wi < mi)) { mv = wv2; mi = wi; }
    }
    ssum += mv;
    if (tid == mi) { sel = 1; val = -3.0e38f; }
    __syncthreads();
  }
  float o = sel ? dense / (ssum + 1e-8f) : 0.f;
  int row = (g == 0) ? 0 : (g == 1) ? 1 : 3;
  out[((size_t)row * BB + b) * 512 + tid] = o;
  if (g == 1) out[((size_t)2 * BB + b) * 512 + tid] = o;
}

extern "C" void kernel_launch(void* const* d_in, const int* in_sizes, int n_in,
                              void* d_out, int out_size, void* d_ws, size_t ws_size,
                              hipStream_t stream) {
  const float* x    = (const float*)d_in[0];
  const float* imp  = (const float*)d_in[1];
  const float* W    = (const float*)d_in[2];
  const float* bias = (const float*)d_in[3];
  const float* emb  = (const float*)d_in[4];
  float* out = (float*)d_out;

  char* ws = (char*)d_ws;
  short* imgH     = (short*)(ws + 0);          // 262144 B
  short* imgL     = (short*)(ws + 262144);     // 262144 B
  short* eH       = (short*)(ws + 524288);     // 196608 B
  short* eL       = (short*)(ws + 720896);     // 196608 B
  short* hH       = (short*)(ws + 917504);     // 2097152 B
  short* hL       = (short*)(ws + 3014656);    // 2097152 B
  float* partials = (float*)(ws + 5111808);    // 12*42*512*4 = 1032192 B

  hipLaunchKernelGGL(k_prep, dim3(416), dim3(256), 0, stream, emb, W, eH, eL, imgH, imgL);
  hipLaunchKernelGGL(k_proj, dim3(512), dim3(256), 0, stream,
                     x, (const float*)imgH, (const float*)imgL, bias, hH, hL);
  hipLaunchKernelGGL(k_pref, dim3(3 * BB * NBB), dim3(512), 0, stream,
                     hH, hL, eH, eL, imp, partials);
  hipLaunchKernelGGL(k_topk, dim3(12), dim3(512), 0, stream, partials, out);
}

// Round 12
// 91.138 us; speedup vs baseline: 1.0068x; 1.0068x over previous
//
#include <hip/hip_runtime.h>

#define NTOT 1536
#define DD 2048
#define BB 4
#define SS 4096
#define NBB 42          // partial blocks per (group,b)
#define TPB 98          // ceil(4096/42)
#define NTILE 7         // 7*16 = 112 >= 98 token slots per block

typedef __attribute__((ext_vector_type(8))) short bf16x8;
typedef __attribute__((ext_vector_type(4))) float f32x4;

__device__ __forceinline__ void split1(float v, unsigned short& hi, unsigned short& lo) {
  unsigned u = __float_as_uint(v);
  hi = (unsigned short)(u >> 16);
  float hf = __uint_as_float(u & 0xffff0000u);
  float r = v - hf;
  lo = (unsigned short)(__float_as_uint(r) >> 16);
}

// async 16B global->LDS (no VGPR round-trip); LDS dest = wave base + lane*16,
// global src is per-lane (pre-swizzled where needed, m173 pattern)
__device__ __forceinline__ void gload16(const void* g, void* lds) {
  __builtin_amdgcn_global_load_lds(
      (const __attribute__((address_space(1))) unsigned int*)g,
      (__attribute__((address_space(3))) unsigned int*)lds, 16, 0, 0);
}

// ---------------- kernel 0: merged prep (emb normalize + W images) -------------
__global__ __launch_bounds__(256) void k_prep(const float* __restrict__ emb,
                                              const float* __restrict__ W,
                                              short* __restrict__ eH,
                                              short* __restrict__ eL,
                                              short* __restrict__ imgH,
                                              short* __restrict__ imgL) {
  int bid = blockIdx.x;
  if (bid < 384) {
    int wave = threadIdx.x >> 6;
    int lane = threadIdx.x & 63;
    int n = bid * 4 + wave;               // 384*4 = 1536 exactly
    float v = emb[n * 64 + lane];
    float ss = v * v;
#pragma unroll
    for (int off = 32; off; off >>= 1) ss += __shfl_xor(ss, off, 64);
    float nrm = fmaxf(sqrtf(ss), 1e-12f);
    float nv = v / nrm;
    unsigned short hi, lo;
    split1(nv, hi, lo);
    eH[n * 64 + lane] = (short)hi;
    eL[n * 64 + lane] = (short)lo;
  } else {
    int kt = bid - 384;                   // 0..31
    for (int idx = threadIdx.x; idx < 4096; idx += 256) {
      int n = idx & 63;
      int q = idx >> 6;          // 0..63
      int p = q >> 3;            // phys slot
      int e = q & 7;
      int s = p ^ (n & 7);       // logical slot
      int k = kt * 64 + s * 8 + e;
      float v = W[k * 64 + n];
      unsigned short hi, lo;
      split1(v, hi, lo);
      int flat = kt * 4096 + n * 64 + p * 8 + e;
      imgH[flat] = (short)hi;
      imgL[flat] = (short)lo;
    }
  }
}

// ---------------- kernel 1: h = x @ W + b via hi/lo bf16 MFMA -> hi/lo h ----------
// unchanged from round 11 (schedule-insensitive: reg-staged / gload_lds /
// counted-vmcnt all within 2 µs)
__global__ __launch_bounds__(256, 2) void k_proj(const float* __restrict__ x,
                                                 const float* __restrict__ imgHf,
                                                 const float* __restrict__ imgLf,
                                                 const float* __restrict__ bias,
                                                 short* __restrict__ hH,
                                                 short* __restrict__ hL) {
  __shared__ float XAs[2][2048];   // [tok 0..31][64 k]; phys slot p holds logical p^(tok&7)
  __shared__ short BHs[2][4096];   // bf16 hi image tile (pre-swizzled in ws)
  __shared__ short BLs[2][4096];

  int tid = threadIdx.x;           // 0..255
  int w = tid >> 6;                // 0..3
  int l = tid & 63;
  size_t t0 = (size_t)blockIdx.x * 32;

  int th = (w & 1) * 16;           // token half
  int nh = (w >> 1) * 32;          // n half

  f32x4 acc[2];
#pragma unroll
  for (int i = 0; i < 2; ++i) acc[i] = (f32x4){0.f, 0.f, 0.f, 0.f};

  const float4* imgH4 = (const float4*)imgHf;
  const float4* imgL4 = (const float4*)imgLf;

  // per-lane staging geometry, constant across kt
  size_t xoff[2];     // float index into x for KT=0 (+= KT*64 per tile)
  int xdst[2];        // float index into XAs[DB]
  int ioff[2];        // float4 index into img (+= KT*512 per tile)
  int bdst[2];        // short index into BHs/BLs[DB]
#pragma unroll
  for (int c = 0; c < 2; ++c) {
    int tok = c * 16 + w * 4 + (l >> 4);
    int s = (l & 15) ^ (tok & 7);                 // logical slot for this phys slot
    xoff[c] = (t0 + tok) * DD + s * 4;
    xdst[c] = tok * 64 + (l & 15) * 4;            // == wave base + l*16B (linear)
    ioff[c] = c * 256 + tid;
    bdst[c] = (c * 256 + tid) * 8;                // == wave base + l*16B (linear)
  }

#define STAGE(DB, KT)                                                        \
  {                                                                          \
    _Pragma("unroll") for (int c = 0; c < 2; ++c) {                          \
      gload16(x + xoff[c] + (KT) * 64, &XAs[DB][xdst[c]]);                   \
      gload16(imgH4 + (KT) * 512 + ioff[c], &BHs[DB][bdst[c]]);              \
      gload16(imgL4 + (KT) * 512 + ioff[c], &BLs[DB][bdst[c]]);              \
    }                                                                        \
  }

#define COMPUTE(DB)                                                                \
  {                                                                                \
    int row = th + (l & 15);                                                       \
    _Pragma("unroll") for (int ks = 0; ks < 2; ++ks) {                             \
      int s0 = ks * 8 + (l >> 4) * 2;                                              \
      float4 xa = *(const float4*)(&XAs[DB][row * 64 + ((s0 ^ (row & 7)) << 2)]);  \
      float4 xb = *(const float4*)(&XAs[DB][row * 64 + (((s0 + 1) ^ (row & 7)) << 2)]); \
      bf16x8 ahi, alo;                                                             \
      {                                                                            \
        float v[8] = {xa.x, xa.y, xa.z, xa.w, xb.x, xb.y, xb.z, xb.w};             \
        _Pragma("unroll") for (int i = 0; i < 8; ++i) {                            \
          unsigned u = __float_as_uint(v[i]);                                      \
          ahi[i] = (short)(u >> 16);                                               \
          float hf = __uint_as_float(u & 0xffff0000u);                             \
          float r = v[i] - hf;                                                     \
          alo[i] = (short)(__float_as_uint(r) >> 16);                              \
        }                                                                          \
      }                                                                            \
      _Pragma("unroll") for (int nf = 0; nf < 2; ++nf) {                           \
        int n = nh + nf * 16 + (l & 15);                                           \
        int p = (ks * 4 + (l >> 4)) ^ (n & 7);                                     \
        bf16x8 bh = *(const bf16x8*)(&BHs[DB][n * 64 + p * 8]);                    \
        bf16x8 bl = *(const bf16x8*)(&BLs[DB][n * 64 + p * 8]);                    \
        acc[nf] = __builtin_amdgcn_mfma_f32_16x16x32_bf16(ahi, bh, acc[nf], 0, 0, 0); \
        acc[nf] = __builtin_amdgcn_mfma_f32_16x16x32_bf16(alo, bh, acc[nf], 0, 0, 0); \
        acc[nf] = __builtin_amdgcn_mfma_f32_16x16x32_bf16(ahi, bl, acc[nf], 0, 0, 0); \
      }                                                                            \
    }                                                                              \
  }

  // depth-2 prologue: tiles 0 and 1 in flight (12 outstanding vmem/wave)
  STAGE(0, 0);
  STAGE(1, 1);

  int db = 0;
#pragma unroll 1
  for (int kt = 0; kt < 32; ++kt) {
    // wait for tile kt's 6 loads; tile kt+1's 6 stay in flight (last iter: 0)
    if (kt < 31) {
      asm volatile("s_waitcnt vmcnt(6)" ::: "memory");
    } else {
      asm volatile("s_waitcnt vmcnt(0)" ::: "memory");
    }
    __builtin_amdgcn_sched_barrier(0);
    __builtin_amdgcn_s_barrier();        // buf[db] ready for all waves
    __builtin_amdgcn_sched_barrier(0);
    COMPUTE(db);
    __builtin_amdgcn_sched_barrier(0);
    __builtin_amdgcn_s_barrier();        // all waves done reading buf[db]
    __builtin_amdgcn_sched_barrier(0);
    if (kt < 30) STAGE(db, kt + 2);      // safe to overwrite now
    db ^= 1;
  }

  // epilogue: token = t0 + th + (l>>4)*4+j, n = nh + nf*16 + (l&15)
#pragma unroll
  for (int nf = 0; nf < 2; ++nf) {
    int n = nh + nf * 16 + (l & 15);
    float bv = bias[n];
#pragma unroll
    for (int j = 0; j < 4; ++j) {
      size_t tok = t0 + th + (l >> 4) * 4 + j;
      float v = acc[nf][j] + bv;
      unsigned short hi, lo;
      split1(v, hi, lo);
      hH[tok * 64 + n] = (short)hi;
      hL[tok * 64 + n] = (short)lo;
    }
  }
#undef STAGE
#undef COMPUTE
}

// ---------------- kernel 2: MFMA logits -> softmax -> importance pooling ----------
// OCCUPANCY-CRITICAL: 512 thr -> 2 blocks/CU (16 waves) requires VGPR <= 128
// exactly (cliff at 129). launch_bounds(512,4) pins the cap at 128; the A-tile
// prefetch from round 8 (+16 VGPR, demand ~136 -> 1 block/CU, 2 generations,
// no barrier-bubble filling) is REMOVED to bring demand to ~105 (no spill).
__global__ __launch_bounds__(512, 4) void k_pref(const short* __restrict__ hH,
                                                 const short* __restrict__ hL,
                                                 const short* __restrict__ eH,
                                                 const short* __restrict__ eL,
                                                 const float* __restrict__ imp,
                                                 float* __restrict__ partials) {
  int bid = blockIdx.x;
  int g = bid / (BB * NBB);
  int rem = bid % (BB * NBB);
  int b = rem / NBB;
  int nb = rem % NBB;
  int tid = threadIdx.x;
  int w = tid >> 6;
  int l = tid & 63;
  int col = l & 15;
  int q = l >> 4;

  __shared__ short BLs[4 * 2 * 512 * 8];   // 65536 B: [nf][ks][tid] 16B slots
  __shared__ float zred[2][8][16];

  bf16x8 BH[4][2];
  {
    const short* eHg = eH + ((size_t)(g * 512 + w * 64 + col)) * 64 + q * 8;
    const short* eLg = eL + ((size_t)(g * 512 + w * 64 + col)) * 64 + q * 8;
#pragma unroll
    for (int nf = 0; nf < 4; ++nf) {
#pragma unroll
      for (int ks = 0; ks < 2; ++ks) {
        BH[nf][ks] = *(const bf16x8*)(eHg + nf * 1024 + ks * 32);
        bf16x8 blv = *(const bf16x8*)(eLg + nf * 1024 + ks * 32);
        *(bf16x8*)(&BLs[((nf * 2 + ks) * 512 + tid) * 8]) = blv;
      }
    }
  }
  __syncthreads();

  int s0 = nb * TPB;
  int slim = s0 + TPB; if (slim > SS) slim = SS;
  float wsum[4] = {0.f, 0.f, 0.f, 0.f};
  int par = 0;

#pragma unroll 1
  for (int tile = 0; tile < NTILE; ++tile) {
    int tbase = s0 + tile * 16;
    int arow = tbase + col; if (arow > SS - 1) arow = SS - 1;
    size_t hoff = ((size_t)b * SS + arow) * 64;
    bf16x8 AH0 = *(const bf16x8*)(hH + hoff + q * 8);
    bf16x8 AH1 = *(const bf16x8*)(hH + hoff + 32 + q * 8);
    bf16x8 AL0 = *(const bf16x8*)(hL + hoff + q * 8);
    bf16x8 AL1 = *(const bf16x8*)(hL + hoff + 32 + q * 8);

    f32x4 acc[4];
#pragma unroll
    for (int nf = 0; nf < 4; ++nf) acc[nf] = (f32x4){0.f, 0.f, 0.f, 0.f};
#pragma unroll
    for (int nf = 0; nf < 4; ++nf) {
      bf16x8 bl0 = *(const bf16x8*)(&BLs[((nf * 2 + 0) * 512 + tid) * 8]);
      bf16x8 bl1 = *(const bf16x8*)(&BLs[((nf * 2 + 1) * 512 + tid) * 8]);
      acc[nf] = __builtin_amdgcn_mfma_f32_16x16x32_bf16(AH0, BH[nf][0], acc[nf], 0, 0, 0);
      acc[nf] = __builtin_amdgcn_mfma_f32_16x16x32_bf16(AL0, BH[nf][0], acc[nf], 0, 0, 0);
      acc[nf] = __builtin_amdgcn_mfma_f32_16x16x32_bf16(AH0, bl0, acc[nf], 0, 0, 0);
      acc[nf] = __builtin_amdgcn_mfma_f32_16x16x32_bf16(AH1, BH[nf][1], acc[nf], 0, 0, 0);
      acc[nf] = __builtin_amdgcn_mfma_f32_16x16x32_bf16(AL1, BH[nf][1], acc[nf], 0, 0, 0);
      acc[nf] = __builtin_amdgcn_mfma_f32_16x16x32_bf16(AH1, bl1, acc[nf], 0, 0, 0);
    }

    float zp[4];
#pragma unroll
    for (int j = 0; j < 4; ++j) {
      zp[j] = __expf(acc[0][j]) + __expf(acc[1][j]) +
              __expf(acc[2][j]) + __expf(acc[3][j]);
    }
#pragma unroll
    for (int off = 1; off <= 8; off <<= 1) {
#pragma unroll
      for (int j = 0; j < 4; ++j) zp[j] += __shfl_xor(zp[j], off, 64);
    }
    float zw = (col == 0) ? zp[0] : (col == 1) ? zp[1] : (col == 2) ? zp[2] : zp[3];
    if (col < 4) zred[par][w][q * 4 + col] = zw;
    __syncthreads();
    float r0, r1, r2, r3;
    {
#pragma unroll
      for (int j = 0; j < 4; ++j) {
        int t16 = q * 4 + j;
        float Z = 0.f;
#pragma unroll
        for (int ww = 0; ww < 8; ++ww) Z += zred[par][ww][t16];
        int s = tbase + t16;
        float iv = (s < slim) ? imp[(size_t)b * SS + s] : 0.f;
        float r = iv / Z;
        if (j == 0) r0 = r; else if (j == 1) r1 = r; else if (j == 2) r2 = r; else r3 = r;
      }
    }
#pragma unroll
    for (int nf = 0; nf < 4; ++nf) {
      wsum[nf] += __expf(acc[nf][0]) * r0 + __expf(acc[nf][1]) * r1 +
                  __expf(acc[nf][2]) * r2 + __expf(acc[nf][3]) * r3;
    }
    par ^= 1;
  }

#pragma unroll
  for (int nf = 0; nf < 4; ++nf) {
    wsum[nf] += __shfl_xor(wsum[nf], 16, 64);
    wsum[nf] += __shfl_xor(wsum[nf], 32, 64);
  }
  if (q == 0) {
    size_t base = ((size_t)(g * BB + b) * NBB + nb) * 512 + w * 64;
#pragma unroll
    for (int nf = 0; nf < 4; ++nf) partials[base + nf * 16 + col] = wsum[nf];
  }
}

// ---------------- kernel 3: reduce partials + top-k + renormalize ----------------
__global__ __launch_bounds__(512) void k_topk(const float* __restrict__ partials,
                                              float* __restrict__ out) {
  int g = blockIdx.x >> 2;   // 0..2
  int b = blockIdx.x & 3;
  int tid = threadIdx.x;     // neuron 0..511
  int wave = tid >> 6, lane = tid & 63;

  __shared__ float lv[8][8];
  __shared__ int li[8][8];

  // 4-way ILP partial sum
  float d0 = 0.f, d1 = 0.f, d2 = 0.f, d3 = 0.f;
  const float* p = partials + (size_t)(g * BB + b) * NBB * 512 + tid;
  int nb = 0;
  for (; nb + 4 <= NBB; nb += 4) {
    d0 += p[(nb + 0) * 512];
    d1 += p[(nb + 1) * 512];
    d2 += p[(nb + 2) * 512];
    d3 += p[(nb + 3) * 512];
  }
  for (; nb < NBB; ++nb) d0 += p[nb * 512];
  float dense = (d0 + d1) + (d2 + d3);

  int K = (g == 0) ? 8 : (g == 1) ? 4 : 6;
  float val = dense;
  float ssum = 0.f;
  int sel = 0;
  for (int it = 0; it < K; ++it) {
    float v = val;
    int idx = tid;
#pragma unroll
    for (int off = 32; off; off >>= 1) {
      float ov = __shfl_xor(v, off, 64);
      int oi = __shfl_xor(idx, off, 64);
      if (ov > v || (ov == v && oi < idx)) { v = ov; idx = oi; }
    }
    if (lane == 0) { lv[wave][0] = v; li[wave][0] = idx; }
    __syncthreads();
    float mv = lv[0][0];
    int mi = li[0][0];
#pragma unroll
    for (int ww = 1; ww < 8; ++ww) {
      float wv2 = lv[ww][0];
      int wi = li[ww][0];
      if (wv2 > mv || (wv2 == mv && wi < mi)) { mv = wv2; mi = wi; }
    }
    ssum += mv;
    if (tid == mi) { sel = 1; val = -3.0e38f; }
    __syncthreads();
  }
  float o = sel ? dense / (ssum + 1e-8f) : 0.f;
  int row = (g == 0) ? 0 : (g == 1) ? 1 : 3;
  out[((size_t)row * BB + b) * 512 + tid] = o;
  if (g == 1) out[((size_t)2 * BB + b) * 512 + tid] = o;
}

extern "C" void kernel_launch(void* const* d_in, const int* in_sizes, int n_in,
                              void* d_out, int out_size, void* d_ws, size_t ws_size,
                              hipStream_t stream) {
  const float* x    = (const float*)d_in[0];
  const float* imp  = (const float*)d_in[1];
  const float* W    = (const float*)d_in[2];
  const float* bias = (const float*)d_in[3];
  const float* emb  = (const float*)d_in[4];
  float* out = (float*)d_out;

  char* ws = (char*)d_ws;
  short* imgH     = (short*)(ws + 0);          // 262144 B
  short* imgL     = (short*)(ws + 262144);     // 262144 B
  short* eH       = (short*)(ws + 524288);     // 196608 B
  short* eL       = (short*)(ws + 720896);     // 196608 B
  short* hH       = (short*)(ws + 917504);     // 2097152 B
  short* hL       = (short*)(ws + 3014656);    // 2097152 B
  float* partials = (float*)(ws + 5111808);    // 12*42*512*4 = 1032192 B

  hipLaunchKernelGGL(k_prep, dim3(416), dim3(256), 0, stream, emb, W, eH, eL, imgH, imgL);
  hipLaunchKernelGGL(k_proj, dim3(512), dim3(256), 0, stream,
                     x, (const float*)imgH, (const float*)imgL, bias, hH, hL);
  hipLaunchKernelGGL(k_pref, dim3(3 * BB * NBB), dim3(512), 0, stream,
                     hH, hL, eH, eL, imp, partials);
  hipLaunchKernelGGL(k_topk, dim3(12), dim3(512), 0, stream, partials, out);
}